// Round 2
// 749.181 us; speedup vs baseline: 1.0940x; 1.0940x over previous
//
#include <hip/hip_runtime.h>
#include <hip/hip_bf16.h>

#define T_TOK 1024
#define NEXP 16
#define HD 2048
#define TOPK 6

typedef __attribute__((ext_vector_type(8))) short short8;
typedef __attribute__((ext_vector_type(4))) float floatx4;

__device__ __forceinline__ short f2bf(float f) {
    unsigned u = __builtin_bit_cast(unsigned, f);
    u += 0x7FFFu + ((u >> 16) & 1u);
    return (short)(u >> 16);
}

typedef __attribute__((address_space(1))) void gvoid;
typedef __attribute__((address_space(3))) void lvoid;
__device__ __forceinline__ void gload_lds16(const void* g, void* l) {
    __builtin_amdgcn_global_load_lds((gvoid*)g, (lvoid*)l, 16, 0, 0);
}

// s_waitcnt imm (gfx9): vmcnt[3:0|15:14], expcnt[6:4], lgkmcnt[11:8]
#define WAITCNT_VM4 0x0F74   // vmcnt(4), lgkm/exp no-wait
#define WAITCNT_VM0 0x0F70   // vmcnt(0)

// ---------------- merged router + fp32->bf16 convert -------------------------
// blocks [0,256): router, 4 tokens/block (one 64-lane wave per token).
// blocks [256,..): grid-stride convert in 8-float chunks:
//   2x floatx4 nontemporal loads (32B/lane) -> 1x short8 store (16B/lane).
// nt loads keep the dead fp32 stream evict-first so bf16 outputs stay in L3
// for the GEMMs.
__global__ __launch_bounds__(256) void router_cvt(
    const float* __restrict__ X, const float* __restrict__ GW,
    const float* __restrict__ bias, int* __restrict__ counts,
    int* __restrict__ lists, int* __restrict__ tok_e,
    int* __restrict__ tok_pos, float* __restrict__ tok_w,
    const float* __restrict__ W1, const float* __restrict__ W2,
    const float* __restrict__ SW1, const float* __restrict__ SW2,
    short* __restrict__ Xb, short* __restrict__ W1b, short* __restrict__ W2b,
    short* __restrict__ SW1b, short* __restrict__ SW2b)
{
    if (blockIdx.x < 256) {
        // ---- router role ----
        const int wave = threadIdx.x >> 6;
        const int l = threadIdx.x & 63;
        const int t = blockIdx.x * 4 + wave;
        const float* x = X + (size_t)t * HD;
        float acc[NEXP];
#pragma unroll
        for (int e = 0; e < NEXP; ++e) acc[e] = 0.f;
        for (int k = l; k < HD; k += 64) {
            const float xv = x[k];
#pragma unroll
            for (int e = 0; e < NEXP; ++e) acc[e] += xv * GW[e * HD + k];
        }
#pragma unroll
        for (int e = 0; e < NEXP; ++e) {
            float v = acc[e];
#pragma unroll
            for (int m = 32; m >= 1; m >>= 1) v += __shfl_xor(v, m, 64);
            acc[e] = v;
        }
        if (l == 0) {
            float s[NEXP], choice[NEXP];
#pragma unroll
            for (int e = 0; e < NEXP; ++e) {
                s[e] = 1.f / (1.f + __expf(-acc[e]));
                choice[e] = s[e] + bias[e];
            }
            int idx[TOPK]; float wv[TOPK]; float wsum = 0.f;
            bool used[NEXP];
#pragma unroll
            for (int e = 0; e < NEXP; ++e) used[e] = false;
            for (int j = 0; j < TOPK; ++j) {
                float best = -1e30f; int bi = 0;
                for (int e = 0; e < NEXP; ++e)
                    if (!used[e] && choice[e] > best) { best = choice[e]; bi = e; }
                used[bi] = true; idx[j] = bi; wv[j] = s[bi]; wsum += s[bi];
            }
            const float scale = 2.5f / wsum;
            for (int j = 0; j < TOPK; ++j) {
                const int e = idx[j];
                const int pos = atomicAdd(&counts[e], 1);
                lists[e * T_TOK + pos] = t;
                tok_e[t * TOPK + j] = e;
                tok_pos[t * TOPK + j] = pos;
                tok_w[t * TOPK + j] = wv[j] * scale;
            }
        }
        return;
    }
    // ---- convert role (8-float chunks) ----
    const int C0 = 262144;           // X    [1024*2048]/8
    const int C1 = C0 + 8388608;     // W1   [16*2048*2048]/8
    const int C2 = C1 + 4194304;     // W2   [16*2048*1024]/8
    const int C3 = C2 + 1048576;     // SW1  [4096*2048]/8
    const int C4 = C3 + 524288;      // SW2  [2048*2048]/8  -> 14417920 total
    const int stride = (gridDim.x - 256) * 256;
#pragma unroll 2
    for (int i = (int)(blockIdx.x - 256) * 256 + (int)threadIdx.x; i < C4;
         i += stride) {
        const float* s; short* d; int l;
        if (i < C0)      { s = X;   d = Xb;   l = i; }
        else if (i < C1) { s = W1;  d = W1b;  l = i - C0; }
        else if (i < C2) { s = W2;  d = W2b;  l = i - C1; }
        else if (i < C3) { s = SW1; d = SW1b; l = i - C2; }
        else             { s = SW2; d = SW2b; l = i - C3; }
        const floatx4 v0 = __builtin_nontemporal_load(((const floatx4*)s) + 2 * l);
        const floatx4 v1 = __builtin_nontemporal_load(((const floatx4*)s) + 2 * l + 1);
        short8 o;
        o[0] = f2bf(v0[0]); o[1] = f2bf(v0[1]); o[2] = f2bf(v0[2]); o[3] = f2bf(v0[3]);
        o[4] = f2bf(v1[0]); o[5] = f2bf(v1[1]); o[6] = f2bf(v1[2]); o[7] = f2bf(v1[3]);
        ((short8*)d)[l] = o;
    }
}

// ---------------- offsets + compacted tile descriptors -----------------------
// desc = (z<<16)|(y<<8)|x ; shared tiles (z=16) first, routed after.
__global__ __launch_bounds__(256) void offsets_descs(
    const int* __restrict__ counts, int* __restrict__ offs,
    int* __restrict__ gu, int* __restrict__ gu_n,
    int* __restrict__ dn, int* __restrict__ dn_n)
{
    __shared__ int base_gu[NEXP], base_dn[NEXP], nys[NEXP];
    if (threadIdx.x == 0) {
        int a = 0, bg = 256, bd = 128;
        for (int e = 0; e < NEXP; ++e) {
            offs[e] = a; a += counts[e];
            const int ny = (counts[e] + 127) >> 7;
            nys[e] = ny; base_gu[e] = bg; base_dn[e] = bd;
            bg += ny * 16; bd += ny * 16;
        }
        *gu_n = bg; *dn_n = bd;
    }
    __syncthreads();
    for (int i = threadIdx.x; i < 256; i += 256)
        gu[i] = (NEXP << 16) | ((i >> 5) << 8) | (i & 31);
    for (int i = threadIdx.x; i < 128; i += 256)
        dn[i] = (NEXP << 16) | ((i >> 4) << 8) | (i & 15);
    for (int e = 0; e < NEXP; ++e) {
        const int nt = nys[e] * 16;
        for (int i = threadIdx.x; i < nt; i += 256) {
            const int v = (e << 16) | ((i >> 4) << 8) | (i & 15);
            gu[base_gu[e] + i] = v;
            dn[base_dn[e] + i] = v;
        }
    }
}

// ======= gate_up GEMM: 3-buffer pipeline, raw barrier + vmcnt(4) =============
// z<16: routed expert (Ih=1024, gathered rows). z==16: shared (Ih=2048, dense).
// Tile 128 tokens x (64 gate + 64 up), BK=32, 4 waves (2x2).
// LDS K-chunk XOR swizzle: global chunk (lane&3)^((lane>>3)&3) lands at
// lane*16; frag col = (l4 ^ ((l15>>1)&3))*8 -> 2-way bank aliasing (free).
__global__ __launch_bounds__(256) void gateup3(
    const short* __restrict__ Xbf, const short* __restrict__ W1bf,
    const short* __restrict__ SW1bf,
    const int* __restrict__ counts, const int* __restrict__ offs,
    const int* __restrict__ lists, const int* __restrict__ descs,
    const int* __restrict__ ndesc,
    short* __restrict__ h_r, short* __restrict__ h_s)
{
    __shared__ short sA[3][128][32];
    __shared__ short sB[3][128][32];
    if ((int)blockIdx.x >= *ndesc) return;
    const int d = descs[blockIdx.x];
    const int z = d >> 16, yb = (d >> 8) & 255, xb = d & 255;
    const bool shx = (z == NEXP);
    const int cnt = shx ? T_TOK : counts[z];
    const int m0 = yb * 128;
    if (m0 >= cnt) return;
    const int Ih = shx ? 2048 : 1024;
    const int i0 = xb * 64;
    const short* W = shx ? SW1bf : (W1bf + (size_t)z * 2048 * HD);
    short* Hout = shx ? h_s : h_r;
    const int hbase = shx ? 0 : offs[z];

    const int tid = threadIdx.x;
    const int wave = tid >> 6, lane = tid & 63;
    const int srow0 = wave * 32 + (lane >> 2);   // 16 rows per wave-instr
    const int srow1 = srow0 + 16;
    const int scol = ((lane & 3) ^ ((lane >> 3) & 3)) * 8;  // swizzled 16B chunk

    int ar0 = m0 + srow0; if (ar0 > cnt - 1) ar0 = cnt - 1;
    int ar1 = m0 + srow1; if (ar1 > cnt - 1) ar1 = cnt - 1;
    const int tok0 = shx ? ar0 : lists[z * T_TOK + ar0];
    const int tok1 = shx ? ar1 : lists[z * T_TOK + ar1];
    const short* ag0 = Xbf + (size_t)tok0 * HD + scol;
    const short* ag1 = Xbf + (size_t)tok1 * HD + scol;
    const int br0 = (srow0 < 64) ? (i0 + srow0) : (Ih + i0 + srow0 - 64);
    const int br1 = (srow1 < 64) ? (i0 + srow1) : (Ih + i0 + srow1 - 64);
    const short* bg0 = W + (size_t)br0 * HD + scol;
    const short* bg1 = W + (size_t)br1 * HD + scol;

    const int wx = wave & 1, wy = wave >> 1;
    const int l15 = lane & 15, l4 = lane >> 4;
    const int fcol = (l4 ^ ((l15 >> 1) & 3)) * 8;   // swizzled frag read col

    floatx4 acc[4][4];
#pragma unroll
    for (int a = 0; a < 4; ++a)
#pragma unroll
        for (int b = 0; b < 4; ++b) acc[a][b] = (floatx4){0.f, 0.f, 0.f, 0.f};

    const int nsteps = HD / 32;   // 64
    // prologue: stage steps 0,1 into bufs 0,1
#pragma unroll
    for (int pb = 0; pb < 2; ++pb) {
        const int off = pb * 32;
        gload_lds16(ag0 + off, &sA[pb][wave * 32][0]);
        gload_lds16(ag1 + off, &sA[pb][wave * 32 + 16][0]);
        gload_lds16(bg0 + off, &sB[pb][wave * 32][0]);
        gload_lds16(bg1 + off, &sB[pb][wave * 32 + 16][0]);
    }

    int p = 0, q = 2;   // p = buf for step s; q = buf to stage (step s+2)
    for (int s = 0; s < nsteps; ++s) {
        // wait for this step's 4 loads (issued 2 steps ago); keep newer in flight
        if (s + 1 < nsteps) __builtin_amdgcn_s_waitcnt(WAITCNT_VM4);
        else                __builtin_amdgcn_s_waitcnt(WAITCNT_VM0);
        __builtin_amdgcn_s_barrier();
        if (s + 2 < nsteps) {
            const int off = (s + 2) * 32;
            gload_lds16(ag0 + off, &sA[q][wave * 32][0]);
            gload_lds16(ag1 + off, &sA[q][wave * 32 + 16][0]);
            gload_lds16(bg0 + off, &sB[q][wave * 32][0]);
            gload_lds16(bg1 + off, &sB[q][wave * 32 + 16][0]);
        }
        short8 af[4], bfr[4];
#pragma unroll
        for (int mc = 0; mc < 4; ++mc)
            af[mc] = *(const short8*)&sA[p][wy * 64 + mc * 16 + l15][fcol];
#pragma unroll
        for (int cb = 0; cb < 4; ++cb) {
            const int br = ((cb < 2) ? 0 : 64) + wx * 32 + (cb & 1) * 16 + l15;
            bfr[cb] = *(const short8*)&sB[p][br][fcol];
        }
#pragma unroll
        for (int mc = 0; mc < 4; ++mc)
#pragma unroll
            for (int cb = 0; cb < 4; ++cb)
                acc[mc][cb] = __builtin_amdgcn_mfma_f32_16x16x32_bf16(
                    af[mc], bfr[cb], acc[mc][cb], 0, 0, 0);
        p = (p == 2) ? 0 : p + 1;
        q = (q == 2) ? 0 : q + 1;
    }

#pragma unroll
    for (int mc = 0; mc < 4; ++mc)
#pragma unroll
        for (int cb = 0; cb < 2; ++cb)
#pragma unroll
            for (int r = 0; r < 4; ++r) {
                const int mrel = wy * 64 + mc * 16 + l4 * 4 + r;
                if (m0 + mrel < cnt) {
                    const float g = acc[mc][cb][r];
                    const float u = acc[mc][cb + 2][r];
                    const float h = g / (1.f + __expf(-g)) * u;
                    const int col = i0 + wx * 32 + cb * 16 + l15;
                    Hout[(size_t)(hbase + m0 + mrel) * Ih + col] = f2bf(h);
                }
            }
}

// ======= down GEMM: same pipeline, dense stores (no atomics) =================
__global__ __launch_bounds__(256) void down3(
    const short* __restrict__ h_r, const short* __restrict__ h_s,
    const short* __restrict__ W2bf, const short* __restrict__ SW2bf,
    const int* __restrict__ counts, const int* __restrict__ offs,
    const int* __restrict__ descs, const int* __restrict__ ndesc,
    float* __restrict__ h2, float* __restrict__ sh_out)
{
    __shared__ short sA[3][128][32];
    __shared__ short sB[3][128][32];
    if ((int)blockIdx.x >= *ndesc) return;
    const int d = descs[blockIdx.x];
    const int z = d >> 16, yb = (d >> 8) & 255, xb = d & 255;
    const bool shx = (z == NEXP);
    const int cnt = shx ? T_TOK : counts[z];
    const int m0 = yb * 128;
    if (m0 >= cnt) return;
    const int Kih = shx ? 2048 : 1024;
    const int n0 = xb * 128;
    const short* A = shx ? h_s : h_r;
    const short* W = shx ? SW2bf : (W2bf + (size_t)z * HD * 1024);
    float* outb = shx ? sh_out : h2;
    const int hbase = shx ? 0 : offs[z];

    const int tid = threadIdx.x;
    const int wave = tid >> 6, lane = tid & 63;
    const int srow0 = wave * 32 + (lane >> 2);
    const int srow1 = srow0 + 16;
    const int scol = ((lane & 3) ^ ((lane >> 3) & 3)) * 8;

    int ar0 = m0 + srow0; if (ar0 > cnt - 1) ar0 = cnt - 1;
    int ar1 = m0 + srow1; if (ar1 > cnt - 1) ar1 = cnt - 1;
    const short* ag0 = A + (size_t)(hbase + ar0) * Kih + scol;
    const short* ag1 = A + (size_t)(hbase + ar1) * Kih + scol;
    const short* bg0 = W + (size_t)(n0 + srow0) * Kih + scol;
    const short* bg1 = W + (size_t)(n0 + srow1) * Kih + scol;

    const int wx = wave & 1, wy = wave >> 1;
    const int l15 = lane & 15, l4 = lane >> 4;
    const int fcol = (l4 ^ ((l15 >> 1) & 3)) * 8;

    floatx4 acc[4][4];
#pragma unroll
    for (int a = 0; a < 4; ++a)
#pragma unroll
        for (int b = 0; b < 4; ++b) acc[a][b] = (floatx4){0.f, 0.f, 0.f, 0.f};

    const int nsteps = Kih / 32;   // 32 or 64
#pragma unroll
    for (int pb = 0; pb < 2; ++pb) {
        const int off = pb * 32;
        gload_lds16(ag0 + off, &sA[pb][wave * 32][0]);
        gload_lds16(ag1 + off, &sA[pb][wave * 32 + 16][0]);
        gload_lds16(bg0 + off, &sB[pb][wave * 32][0]);
        gload_lds16(bg1 + off, &sB[pb][wave * 32 + 16][0]);
    }

    int p = 0, q = 2;
    for (int s = 0; s < nsteps; ++s) {
        if (s + 1 < nsteps) __builtin_amdgcn_s_waitcnt(WAITCNT_VM4);
        else                __builtin_amdgcn_s_waitcnt(WAITCNT_VM0);
        __builtin_amdgcn_s_barrier();
        if (s + 2 < nsteps) {
            const int off = (s + 2) * 32;
            gload_lds16(ag0 + off, &sA[q][wave * 32][0]);
            gload_lds16(ag1 + off, &sA[q][wave * 32 + 16][0]);
            gload_lds16(bg0 + off, &sB[q][wave * 32][0]);
            gload_lds16(bg1 + off, &sB[q][wave * 32 + 16][0]);
        }
        short8 af[4], bfr[4];
#pragma unroll
        for (int mc = 0; mc < 4; ++mc)
            af[mc] = *(const short8*)&sA[p][wy * 64 + mc * 16 + l15][fcol];
#pragma unroll
        for (int cb = 0; cb < 4; ++cb)
            bfr[cb] = *(const short8*)&sB[p][wx * 64 + cb * 16 + l15][fcol];
#pragma unroll
        for (int mc = 0; mc < 4; ++mc)
#pragma unroll
            for (int cb = 0; cb < 4; ++cb)
                acc[mc][cb] = __builtin_amdgcn_mfma_f32_16x16x32_bf16(
                    af[mc], bfr[cb], acc[mc][cb], 0, 0, 0);
        p = (p == 2) ? 0 : p + 1;
        q = (q == 2) ? 0 : q + 1;
    }

#pragma unroll
    for (int mc = 0; mc < 4; ++mc)
#pragma unroll
        for (int r = 0; r < 4; ++r) {
            const int mrel = wy * 64 + mc * 16 + l4 * 4 + r;
            if (m0 + mrel >= cnt) continue;
            float* orow = outb + (size_t)(hbase + m0 + mrel) * HD + n0 + wx * 64 + l15;
#pragma unroll
            for (int cb = 0; cb < 4; ++cb)
                orow[cb * 16] = acc[mc][cb][r];
        }
}

// ---------------- combine: out[t] = sh_out[t] + sum_j w_j * h2[row_j] --------
__global__ __launch_bounds__(256) void combine_kernel(
    const float* __restrict__ h2, const float* __restrict__ sh_out,
    const int* __restrict__ offs, const int* __restrict__ tok_e,
    const int* __restrict__ tok_pos, const float* __restrict__ tok_w,
    float* __restrict__ out)
{
    const int t = blockIdx.x;
    int rows[TOPK]; float w[TOPK];
#pragma unroll
    for (int j = 0; j < TOPK; ++j) {
        const int e = tok_e[t * TOPK + j];
        rows[j] = offs[e] + tok_pos[t * TOPK + j];
        w[j] = tok_w[t * TOPK + j];
    }
    for (int c = threadIdx.x * 4; c < HD; c += 256 * 4) {
        float4 acc = *(const float4*)(sh_out + (size_t)t * HD + c);
#pragma unroll
        for (int j = 0; j < TOPK; ++j) {
            const float4 v = *(const float4*)(h2 + (size_t)rows[j] * HD + c);
            acc.x += w[j] * v.x; acc.y += w[j] * v.y;
            acc.z += w[j] * v.z; acc.w += w[j] * v.w;
        }
        *(float4*)(out + (size_t)t * HD + c) = acc;
    }
}

extern "C" void kernel_launch(void* const* d_in, const int* in_sizes, int n_in,
                              void* d_out, int out_size, void* d_ws, size_t ws_size,
                              hipStream_t stream) {
    const float* X    = (const float*)d_in[0];  // [1024,2048]
    const float* GW   = (const float*)d_in[1];  // [16,2048]
    const float* BIAS = (const float*)d_in[2];  // [16]
    const float* W1   = (const float*)d_in[3];  // [16,2048,2048]
    const float* W2   = (const float*)d_in[4];  // [16,2048,1024]
    const float* SW1  = (const float*)d_in[5];  // [4096,2048]
    const float* SW2  = (const float*)d_in[6];  // [2048,2048]
    float* out = (float*)d_out;                 // [1024,2048] fp32

    char* ws = (char*)d_ws;
    int*   counts  = (int*)(ws + 0);            // 64 B
    int*   offs    = (int*)(ws + 64);           // 64 B
    int*   lists   = (int*)(ws + 256);          // 65536 B
    int*   tok_e   = (int*)(ws + 65792);        // 24576 B
    int*   tok_pos = (int*)(ws + 90368);        // 24576 B
    float* tok_w   = (float*)(ws + 114944);     // 24576 B -> ends 139520
    int*   gu_n    = (int*)(ws + 139776);
    int*   dn_n    = (int*)(ws + 139780);
    int*   gu_desc = (int*)(ws + 139840);       // <=1280 ints
    int*   dn_desc = (int*)(ws + 145024);       // <=1152 ints -> ends ~149632
    short* h_r     = (short*)(ws + 262144);     // 6144*1024 bf16 = 12.6 MB
    short* h_s     = (short*)(ws + 12845056);   // 1024*2048 bf16 =  4.2 MB
    float* h2      = (float*)(ws + 17039360);   // 6144*2048 fp32 = 50.3 MB
    float* sh_out  = (float*)(ws + 67371008);   // 1024*2048 fp32 =  8.4 MB
    short* Xbf     = (short*)(ws + 75759616);   //  4.2 MB
    short* W1bf    = (short*)(ws + 79953920);   // 134.2 MB
    short* W2bf    = (short*)(ws + 214171648);  //  67.1 MB
    short* SW1bf   = (short*)(ws + 281280512);  //  16.8 MB
    short* SW2bf   = (short*)(ws + 298057728);  //   8.4 MB
    const size_t WS_NEEDED = 306446336;         // ~306 MB (ws is 1 GiB)
    if (ws_size < WS_NEEDED) return;

    hipMemsetAsync(counts, 0, 64, stream);
    // merged router (blocks 0..255, 4 tokens each) + convert (blocks 256..4351)
    router_cvt<<<4352, 256, 0, stream>>>(X, GW, BIAS, counts, lists,
                                         tok_e, tok_pos, tok_w,
                                         W1, W2, SW1, SW2,
                                         Xbf, W1bf, W2bf, SW1bf, SW2bf);
    offsets_descs<<<1, 256, 0, stream>>>(counts, offs, gu_desc, gu_n,
                                         dn_desc, dn_n);

    // static max grids; tail blocks read ndesc and exit
    gateup3<<<1280, 256, 0, stream>>>(Xbf, W1bf, SW1bf, counts, offs, lists,
                                      gu_desc, gu_n, h_r, h_s);
    down3<<<1152, 256, 0, stream>>>(h_r, h_s, W2bf, SW2bf, counts, offs,
                                    dn_desc, dn_n, h2, sh_out);
    combine_kernel<<<T_TOK, 256, 0, stream>>>(
        h2, sh_out, offs, tok_e, tok_pos, tok_w, out);
}

// Round 3
// 747.803 us; speedup vs baseline: 1.0960x; 1.0018x over previous
//
#include <hip/hip_runtime.h>
#include <hip/hip_bf16.h>

#define T_TOK 1024
#define NEXP 16
#define HD 2048
#define TOPK 6

typedef __attribute__((ext_vector_type(8))) short short8;
typedef __attribute__((ext_vector_type(4))) float floatx4;

__device__ __forceinline__ short f2bf(float f) {
    unsigned u = __builtin_bit_cast(unsigned, f);
    u += 0x7FFFu + ((u >> 16) & 1u);
    return (short)(u >> 16);
}

typedef __attribute__((address_space(1))) void gvoid;
typedef __attribute__((address_space(3))) void lvoid;
__device__ __forceinline__ void gload_lds16(const void* g, void* l) {
    __builtin_amdgcn_global_load_lds((gvoid*)g, (lvoid*)l, 16, 0, 0);
}

// s_waitcnt imm (gfx9): vmcnt[3:0|15:14], expcnt[6:4], lgkmcnt[11:8]
#define WAITCNT_VM4 0x0F74   // vmcnt(4), lgkm/exp no-wait
#define WAITCNT_VM0 0x0F70   // vmcnt(0)

// ---------------- merged router + fp32->bf16 convert (X, W1, SW1 only) ------
// blocks [0,256): router, 4 tokens/block (one 64-lane wave per token).
// blocks [256,..): grid-stride convert in 8-float chunks, plain cached loads
// (round-0 A/B: non-nt measured faster than nt for this pass).
// W2/SW2 conversion is deferred into gateup3's grid (runs in its BW shadow).
__global__ __launch_bounds__(256) void router_cvt(
    const float* __restrict__ X, const float* __restrict__ GW,
    const float* __restrict__ bias, int* __restrict__ counts,
    int* __restrict__ lists, int* __restrict__ tok_e,
    int* __restrict__ tok_pos, float* __restrict__ tok_w,
    const float* __restrict__ W1, const float* __restrict__ SW1,
    short* __restrict__ Xb, short* __restrict__ W1b, short* __restrict__ SW1b)
{
    if (blockIdx.x < 256) {
        // ---- router role ----
        const int wave = threadIdx.x >> 6;
        const int l = threadIdx.x & 63;
        const int t = blockIdx.x * 4 + wave;
        const float* x = X + (size_t)t * HD;
        float acc[NEXP];
#pragma unroll
        for (int e = 0; e < NEXP; ++e) acc[e] = 0.f;
        for (int k = l; k < HD; k += 64) {
            const float xv = x[k];
#pragma unroll
            for (int e = 0; e < NEXP; ++e) acc[e] += xv * GW[e * HD + k];
        }
#pragma unroll
        for (int e = 0; e < NEXP; ++e) {
            float v = acc[e];
#pragma unroll
            for (int m = 32; m >= 1; m >>= 1) v += __shfl_xor(v, m, 64);
            acc[e] = v;
        }
        if (l == 0) {
            float s[NEXP], choice[NEXP];
#pragma unroll
            for (int e = 0; e < NEXP; ++e) {
                s[e] = 1.f / (1.f + __expf(-acc[e]));
                choice[e] = s[e] + bias[e];
            }
            int idx[TOPK]; float wv[TOPK]; float wsum = 0.f;
            bool used[NEXP];
#pragma unroll
            for (int e = 0; e < NEXP; ++e) used[e] = false;
            for (int j = 0; j < TOPK; ++j) {
                float best = -1e30f; int bi = 0;
                for (int e = 0; e < NEXP; ++e)
                    if (!used[e] && choice[e] > best) { best = choice[e]; bi = e; }
                used[bi] = true; idx[j] = bi; wv[j] = s[bi]; wsum += s[bi];
            }
            const float scale = 2.5f / wsum;
            for (int j = 0; j < TOPK; ++j) {
                const int e = idx[j];
                const int pos = atomicAdd(&counts[e], 1);
                lists[e * T_TOK + pos] = t;
                tok_e[t * TOPK + j] = e;
                tok_pos[t * TOPK + j] = pos;
                tok_w[t * TOPK + j] = wv[j] * scale;
            }
        }
        return;
    }
    // ---- convert role (8-float chunks): X, W1, SW1 ----
    const int C0 = 262144;           // X    [1024*2048]/8
    const int C1 = C0 + 8388608;     // W1   [16*2048*2048]/8
    const int C2 = C1 + 1048576;     // SW1  [4096*2048]/8  -> 9699328 total
    const int stride = (gridDim.x - 256) * 256;
#pragma unroll 2
    for (int i = (int)(blockIdx.x - 256) * 256 + (int)threadIdx.x; i < C2;
         i += stride) {
        const float* s; short* d; int l;
        if (i < C0)      { s = X;   d = Xb;   l = i; }
        else if (i < C1) { s = W1;  d = W1b;  l = i - C0; }
        else             { s = SW1; d = SW1b; l = i - C1; }
        const floatx4 v0 = ((const floatx4*)s)[2 * l];
        const floatx4 v1 = ((const floatx4*)s)[2 * l + 1];
        short8 o;
        o[0] = f2bf(v0[0]); o[1] = f2bf(v0[1]); o[2] = f2bf(v0[2]); o[3] = f2bf(v0[3]);
        o[4] = f2bf(v1[0]); o[5] = f2bf(v1[1]); o[6] = f2bf(v1[2]); o[7] = f2bf(v1[3]);
        ((short8*)d)[l] = o;
    }
}

// ---------------- offsets + compacted tile descriptors -----------------------
// desc = (z<<16)|(y<<8)|x ; shared tiles (z=16) first, routed after.
__global__ __launch_bounds__(256) void offsets_descs(
    const int* __restrict__ counts, int* __restrict__ offs,
    int* __restrict__ gu, int* __restrict__ gu_n,
    int* __restrict__ dn, int* __restrict__ dn_n)
{
    __shared__ int base_gu[NEXP], base_dn[NEXP], nys[NEXP];
    if (threadIdx.x == 0) {
        int a = 0, bg = 256, bd = 128;
        for (int e = 0; e < NEXP; ++e) {
            offs[e] = a; a += counts[e];
            const int ny = (counts[e] + 127) >> 7;
            nys[e] = ny; base_gu[e] = bg; base_dn[e] = bd;
            bg += ny * 16; bd += ny * 16;
        }
        *gu_n = bg; *dn_n = bd;
    }
    __syncthreads();
    for (int i = threadIdx.x; i < 256; i += 256)
        gu[i] = (NEXP << 16) | ((i >> 5) << 8) | (i & 31);
    for (int i = threadIdx.x; i < 128; i += 256)
        dn[i] = (NEXP << 16) | ((i >> 4) << 8) | (i & 15);
    for (int e = 0; e < NEXP; ++e) {
        const int nt = nys[e] * 16;
        for (int i = threadIdx.x; i < nt; i += 256) {
            const int v = (e << 16) | ((i >> 4) << 8) | (i & 15);
            gu[base_gu[e] + i] = v;
            dn[base_dn[e] + i] = v;
        }
    }
}

// ======= gate_up GEMM (+ fused W2/SW2 fp32->bf16 convert) ===================
// blocks [0,1280): GEMM tiles (tail past *ndesc exits).
// blocks [1280,...): convert W2/SW2 to bf16 in the GEMM's bandwidth shadow.
//   nt loads: the read-once fp32 stream must not evict W1bf (actively
//   re-read from L3 by the GEMM blocks).
// z<16: routed expert (Ih=1024, gathered rows). z==16: shared (Ih=2048, dense).
// Tile 128 tokens x (64 gate + 64 up), BK=32, 4 waves (2x2).
__global__ __launch_bounds__(256) void gateup3(
    const short* __restrict__ Xbf, const short* __restrict__ W1bf,
    const short* __restrict__ SW1bf,
    const int* __restrict__ counts, const int* __restrict__ offs,
    const int* __restrict__ lists, const int* __restrict__ descs,
    const int* __restrict__ ndesc,
    short* __restrict__ h_r, short* __restrict__ h_s,
    const float* __restrict__ W2f, const float* __restrict__ SW2f,
    short* __restrict__ W2b, short* __restrict__ SW2b)
{
    __shared__ short sA[3][128][32];
    __shared__ short sB[3][128][32];
    if (blockIdx.x >= 1280) {
        // ---- fused convert role: W2 then SW2 ----
        const int CW0 = 4194304;          // W2  [16*2048*1024]/8
        const int CW1 = CW0 + 524288;     // SW2 [2048*2048]/8 -> 4718592
        const int stride = ((int)gridDim.x - 1280) * 256;
#pragma unroll 2
        for (int i = ((int)blockIdx.x - 1280) * 256 + (int)threadIdx.x;
             i < CW1; i += stride) {
            const float* s; short* d; int l;
            if (i < CW0) { s = W2f;  d = W2b;  l = i; }
            else         { s = SW2f; d = SW2b; l = i - CW0; }
            const floatx4 v0 = __builtin_nontemporal_load(((const floatx4*)s) + 2 * l);
            const floatx4 v1 = __builtin_nontemporal_load(((const floatx4*)s) + 2 * l + 1);
            short8 o;
            o[0] = f2bf(v0[0]); o[1] = f2bf(v0[1]); o[2] = f2bf(v0[2]); o[3] = f2bf(v0[3]);
            o[4] = f2bf(v1[0]); o[5] = f2bf(v1[1]); o[6] = f2bf(v1[2]); o[7] = f2bf(v1[3]);
            ((short8*)d)[l] = o;
        }
        return;
    }
    if ((int)blockIdx.x >= *ndesc) return;
    const int d = descs[blockIdx.x];
    const int z = d >> 16, yb = (d >> 8) & 255, xb = d & 255;
    const bool shx = (z == NEXP);
    const int cnt = shx ? T_TOK : counts[z];
    const int m0 = yb * 128;
    if (m0 >= cnt) return;
    const int Ih = shx ? 2048 : 1024;
    const int i0 = xb * 64;
    const short* W = shx ? SW1bf : (W1bf + (size_t)z * 2048 * HD);
    short* Hout = shx ? h_s : h_r;
    const int hbase = shx ? 0 : offs[z];

    const int tid = threadIdx.x;
    const int wave = tid >> 6, lane = tid & 63;
    const int srow0 = wave * 32 + (lane >> 2);   // 16 rows per wave-instr
    const int srow1 = srow0 + 16;
    const int scol = ((lane & 3) ^ ((lane >> 3) & 3)) * 8;  // swizzled 16B chunk

    int ar0 = m0 + srow0; if (ar0 > cnt - 1) ar0 = cnt - 1;
    int ar1 = m0 + srow1; if (ar1 > cnt - 1) ar1 = cnt - 1;
    const int tok0 = shx ? ar0 : lists[z * T_TOK + ar0];
    const int tok1 = shx ? ar1 : lists[z * T_TOK + ar1];
    const short* ag0 = Xbf + (size_t)tok0 * HD + scol;
    const short* ag1 = Xbf + (size_t)tok1 * HD + scol;
    const int br0 = (srow0 < 64) ? (i0 + srow0) : (Ih + i0 + srow0 - 64);
    const int br1 = (srow1 < 64) ? (i0 + srow1) : (Ih + i0 + srow1 - 64);
    const short* bg0 = W + (size_t)br0 * HD + scol;
    const short* bg1 = W + (size_t)br1 * HD + scol;

    const int wx = wave & 1, wy = wave >> 1;
    const int l15 = lane & 15, l4 = lane >> 4;
    const int fcol = (l4 ^ ((l15 >> 1) & 3)) * 8;   // swizzled frag read col

    floatx4 acc[4][4];
#pragma unroll
    for (int a = 0; a < 4; ++a)
#pragma unroll
        for (int b = 0; b < 4; ++b) acc[a][b] = (floatx4){0.f, 0.f, 0.f, 0.f};

    const int nsteps = HD / 32;   // 64
    // prologue: stage steps 0,1 into bufs 0,1
#pragma unroll
    for (int pb = 0; pb < 2; ++pb) {
        const int off = pb * 32;
        gload_lds16(ag0 + off, &sA[pb][wave * 32][0]);
        gload_lds16(ag1 + off, &sA[pb][wave * 32 + 16][0]);
        gload_lds16(bg0 + off, &sB[pb][wave * 32][0]);
        gload_lds16(bg1 + off, &sB[pb][wave * 32 + 16][0]);
    }

    int p = 0, q = 2;   // p = buf for step s; q = buf to stage (step s+2)
    for (int s = 0; s < nsteps; ++s) {
        // wait for this step's 4 loads (issued 2 steps ago); keep newer in flight
        if (s + 1 < nsteps) __builtin_amdgcn_s_waitcnt(WAITCNT_VM4);
        else                __builtin_amdgcn_s_waitcnt(WAITCNT_VM0);
        __builtin_amdgcn_s_barrier();
        if (s + 2 < nsteps) {
            const int off = (s + 2) * 32;
            gload_lds16(ag0 + off, &sA[q][wave * 32][0]);
            gload_lds16(ag1 + off, &sA[q][wave * 32 + 16][0]);
            gload_lds16(bg0 + off, &sB[q][wave * 32][0]);
            gload_lds16(bg1 + off, &sB[q][wave * 32 + 16][0]);
        }
        short8 af[4], bfr[4];
#pragma unroll
        for (int mc = 0; mc < 4; ++mc)
            af[mc] = *(const short8*)&sA[p][wy * 64 + mc * 16 + l15][fcol];
#pragma unroll
        for (int cb = 0; cb < 4; ++cb) {
            const int br = ((cb < 2) ? 0 : 64) + wx * 32 + (cb & 1) * 16 + l15;
            bfr[cb] = *(const short8*)&sB[p][br][fcol];
        }
#pragma unroll
        for (int mc = 0; mc < 4; ++mc)
#pragma unroll
            for (int cb = 0; cb < 4; ++cb)
                acc[mc][cb] = __builtin_amdgcn_mfma_f32_16x16x32_bf16(
                    af[mc], bfr[cb], acc[mc][cb], 0, 0, 0);
        p = (p == 2) ? 0 : p + 1;
        q = (q == 2) ? 0 : q + 1;
    }

#pragma unroll
    for (int mc = 0; mc < 4; ++mc)
#pragma unroll
        for (int cb = 0; cb < 2; ++cb)
#pragma unroll
            for (int r = 0; r < 4; ++r) {
                const int mrel = wy * 64 + mc * 16 + l4 * 4 + r;
                if (m0 + mrel < cnt) {
                    const float g = acc[mc][cb][r];
                    const float u = acc[mc][cb + 2][r];
                    const float h = g / (1.f + __expf(-g)) * u;
                    const int col = i0 + wx * 32 + cb * 16 + l15;
                    Hout[(size_t)(hbase + m0 + mrel) * Ih + col] = f2bf(h);
                }
            }
}

// ======= down GEMM: same pipeline, dense stores (no atomics) =================
__global__ __launch_bounds__(256) void down3(
    const short* __restrict__ h_r, const short* __restrict__ h_s,
    const short* __restrict__ W2bf, const short* __restrict__ SW2bf,
    const int* __restrict__ counts, const int* __restrict__ offs,
    const int* __restrict__ descs, const int* __restrict__ ndesc,
    float* __restrict__ h2, float* __restrict__ sh_out)
{
    __shared__ short sA[3][128][32];
    __shared__ short sB[3][128][32];
    if ((int)blockIdx.x >= *ndesc) return;
    const int d = descs[blockIdx.x];
    const int z = d >> 16, yb = (d >> 8) & 255, xb = d & 255;
    const bool shx = (z == NEXP);
    const int cnt = shx ? T_TOK : counts[z];
    const int m0 = yb * 128;
    if (m0 >= cnt) return;
    const int Kih = shx ? 2048 : 1024;
    const int n0 = xb * 128;
    const short* A = shx ? h_s : h_r;
    const short* W = shx ? SW2bf : (W2bf + (size_t)z * HD * 1024);
    float* outb = shx ? sh_out : h2;
    const int hbase = shx ? 0 : offs[z];

    const int tid = threadIdx.x;
    const int wave = tid >> 6, lane = tid & 63;
    const int srow0 = wave * 32 + (lane >> 2);
    const int srow1 = srow0 + 16;
    const int scol = ((lane & 3) ^ ((lane >> 3) & 3)) * 8;

    int ar0 = m0 + srow0; if (ar0 > cnt - 1) ar0 = cnt - 1;
    int ar1 = m0 + srow1; if (ar1 > cnt - 1) ar1 = cnt - 1;
    const short* ag0 = A + (size_t)(hbase + ar0) * Kih + scol;
    const short* ag1 = A + (size_t)(hbase + ar1) * Kih + scol;
    const short* bg0 = W + (size_t)(n0 + srow0) * Kih + scol;
    const short* bg1 = W + (size_t)(n0 + srow1) * Kih + scol;

    const int wx = wave & 1, wy = wave >> 1;
    const int l15 = lane & 15, l4 = lane >> 4;
    const int fcol = (l4 ^ ((l15 >> 1) & 3)) * 8;

    floatx4 acc[4][4];
#pragma unroll
    for (int a = 0; a < 4; ++a)
#pragma unroll
        for (int b = 0; b < 4; ++b) acc[a][b] = (floatx4){0.f, 0.f, 0.f, 0.f};

    const int nsteps = Kih / 32;   // 32 or 64
#pragma unroll
    for (int pb = 0; pb < 2; ++pb) {
        const int off = pb * 32;
        gload_lds16(ag0 + off, &sA[pb][wave * 32][0]);
        gload_lds16(ag1 + off, &sA[pb][wave * 32 + 16][0]);
        gload_lds16(bg0 + off, &sB[pb][wave * 32][0]);
        gload_lds16(bg1 + off, &sB[pb][wave * 32 + 16][0]);
    }

    int p = 0, q = 2;
    for (int s = 0; s < nsteps; ++s) {
        if (s + 1 < nsteps) __builtin_amdgcn_s_waitcnt(WAITCNT_VM4);
        else                __builtin_amdgcn_s_waitcnt(WAITCNT_VM0);
        __builtin_amdgcn_s_barrier();
        if (s + 2 < nsteps) {
            const int off = (s + 2) * 32;
            gload_lds16(ag0 + off, &sA[q][wave * 32][0]);
            gload_lds16(ag1 + off, &sA[q][wave * 32 + 16][0]);
            gload_lds16(bg0 + off, &sB[q][wave * 32][0]);
            gload_lds16(bg1 + off, &sB[q][wave * 32 + 16][0]);
        }
        short8 af[4], bfr[4];
#pragma unroll
        for (int mc = 0; mc < 4; ++mc)
            af[mc] = *(const short8*)&sA[p][wy * 64 + mc * 16 + l15][fcol];
#pragma unroll
        for (int cb = 0; cb < 4; ++cb)
            bfr[cb] = *(const short8*)&sB[p][wx * 64 + cb * 16 + l15][fcol];
#pragma unroll
        for (int mc = 0; mc < 4; ++mc)
#pragma unroll
            for (int cb = 0; cb < 4; ++cb)
                acc[mc][cb] = __builtin_amdgcn_mfma_f32_16x16x32_bf16(
                    af[mc], bfr[cb], acc[mc][cb], 0, 0, 0);
        p = (p == 2) ? 0 : p + 1;
        q = (q == 2) ? 0 : q + 1;
    }

#pragma unroll
    for (int mc = 0; mc < 4; ++mc)
#pragma unroll
        for (int r = 0; r < 4; ++r) {
            const int mrel = wy * 64 + mc * 16 + l4 * 4 + r;
            if (m0 + mrel >= cnt) continue;
            float* orow = outb + (size_t)(hbase + m0 + mrel) * HD + n0 + wx * 64 + l15;
#pragma unroll
            for (int cb = 0; cb < 4; ++cb)
                orow[cb * 16] = acc[mc][cb][r];
        }
}

// ---------------- combine: out[t] = sh_out[t] + sum_j w_j * h2[row_j] --------
__global__ __launch_bounds__(256) void combine_kernel(
    const float* __restrict__ h2, const float* __restrict__ sh_out,
    const int* __restrict__ offs, const int* __restrict__ tok_e,
    const int* __restrict__ tok_pos, const float* __restrict__ tok_w,
    float* __restrict__ out)
{
    const int t = blockIdx.x;
    int rows[TOPK]; float w[TOPK];
#pragma unroll
    for (int j = 0; j < TOPK; ++j) {
        const int e = tok_e[t * TOPK + j];
        rows[j] = offs[e] + tok_pos[t * TOPK + j];
        w[j] = tok_w[t * TOPK + j];
    }
    for (int c = threadIdx.x * 4; c < HD; c += 256 * 4) {
        float4 acc = *(const float4*)(sh_out + (size_t)t * HD + c);
#pragma unroll
        for (int j = 0; j < TOPK; ++j) {
            const float4 v = *(const float4*)(h2 + (size_t)rows[j] * HD + c);
            acc.x += w[j] * v.x; acc.y += w[j] * v.y;
            acc.z += w[j] * v.z; acc.w += w[j] * v.w;
        }
        *(float4*)(out + (size_t)t * HD + c) = acc;
    }
}

extern "C" void kernel_launch(void* const* d_in, const int* in_sizes, int n_in,
                              void* d_out, int out_size, void* d_ws, size_t ws_size,
                              hipStream_t stream) {
    const float* X    = (const float*)d_in[0];  // [1024,2048]
    const float* GW   = (const float*)d_in[1];  // [16,2048]
    const float* BIAS = (const float*)d_in[2];  // [16]
    const float* W1   = (const float*)d_in[3];  // [16,2048,2048]
    const float* W2   = (const float*)d_in[4];  // [16,2048,1024]
    const float* SW1  = (const float*)d_in[5];  // [4096,2048]
    const float* SW2  = (const float*)d_in[6];  // [2048,2048]
    float* out = (float*)d_out;                 // [1024,2048] fp32

    char* ws = (char*)d_ws;
    int*   counts  = (int*)(ws + 0);            // 64 B
    int*   offs    = (int*)(ws + 64);           // 64 B
    int*   lists   = (int*)(ws + 256);          // 65536 B
    int*   tok_e   = (int*)(ws + 65792);        // 24576 B
    int*   tok_pos = (int*)(ws + 90368);        // 24576 B
    float* tok_w   = (float*)(ws + 114944);     // 24576 B -> ends 139520
    int*   gu_n    = (int*)(ws + 139776);
    int*   dn_n    = (int*)(ws + 139780);
    int*   gu_desc = (int*)(ws + 139840);       // <=1280 ints
    int*   dn_desc = (int*)(ws + 145024);       // <=1152 ints -> ends ~149632
    short* h_r     = (short*)(ws + 262144);     // 6144*1024 bf16 = 12.6 MB
    short* h_s     = (short*)(ws + 12845056);   // 1024*2048 bf16 =  4.2 MB
    float* h2      = (float*)(ws + 17039360);   // 6144*2048 fp32 = 50.3 MB
    float* sh_out  = (float*)(ws + 67371008);   // 1024*2048 fp32 =  8.4 MB
    short* Xbf     = (short*)(ws + 75759616);   //  4.2 MB
    short* W1bf    = (short*)(ws + 79953920);   // 134.2 MB
    short* W2bf    = (short*)(ws + 214171648);  //  67.1 MB
    short* SW1bf   = (short*)(ws + 281280512);  //  16.8 MB
    short* SW2bf   = (short*)(ws + 298057728);  //   8.4 MB
    const size_t WS_NEEDED = 306446336;         // ~306 MB (ws is 1 GiB)
    if (ws_size < WS_NEEDED) return;

    hipMemsetAsync(counts, 0, 64, stream);
    // merged router (blocks 0..255, 4 tokens each) + convert X/W1/SW1
    router_cvt<<<4352, 256, 0, stream>>>(X, GW, BIAS, counts, lists,
                                         tok_e, tok_pos, tok_w,
                                         W1, SW1, Xbf, W1bf, SW1bf);
    offsets_descs<<<1, 256, 0, stream>>>(counts, offs, gu_desc, gu_n,
                                         dn_desc, dn_n);

    // GEMM blocks [0,1280) + fused W2/SW2 convert blocks [1280,3328)
    gateup3<<<3328, 256, 0, stream>>>(Xbf, W1bf, SW1bf, counts, offs, lists,
                                      gu_desc, gu_n, h_r, h_s,
                                      W2, SW2, W2bf, SW2bf);
    down3<<<1152, 256, 0, stream>>>(h_r, h_s, W2bf, SW2bf, counts, offs,
                                    dn_desc, dn_n, h2, sh_out);
    combine_kernel<<<T_TOK, 256, 0, stream>>>(
        h2, sh_out, offs, tok_e, tok_pos, tok_w, out);
}